// Round 7
// baseline (187.767 us; speedup 1.0000x reference)
//
#include <hip/hip_runtime.h>
#include <cstdint>
#include <cstddef>

#define NEG_ (-1e25f)

typedef __bf16 bf16x8 __attribute__((ext_vector_type(8)));
typedef float  f32x4  __attribute__((ext_vector_type(4)));
typedef short  s16x8  __attribute__((ext_vector_type(8)));
typedef const __attribute__((address_space(1))) void* gas_t;
typedef __attribute__((address_space(3))) void* las_t;

#define MFMA16 __builtin_amdgcn_mfma_f32_16x16x32_bf16

__device__ __forceinline__ short f2bf(float f) {
  union { float f; unsigned u; } v; v.f = f;
  unsigned r = v.u + 0x7fffu + ((v.u >> 16) & 1u);  // RNE
  return (short)(r >> 16);
}

__device__ __forceinline__ s16x8 cvt8(const float* s) {
  bf16x8 r;
  #pragma unroll
  for (int j = 0; j < 8; ++j) r[j] = (__bf16)s[j];  // fptrunc = RNE
  union { bf16x8 b; s16x8 s; } u; u.b = r; return u.s;
}

// ---- f32-input 64x64 GEMM: C_bf16 = A_f32[M,K] @ B_f32[N,K]^T ----
// PD=2 LDS + 2-deep register prefetch, ONE barrier/iter.
// lds layout: buf s at lds + s*4096 (As 2048 shorts, Bs 2048 shorts).
template <int NT>
__device__ void fgemm64(const float* __restrict__ A, long lda,
                        const float* __restrict__ B, long ldb,
                        short* __restrict__ C, int ldc, int m0, int n0,
                        short* lds) {
  const int tid = threadIdx.x, wave = tid >> 6, lane = tid & 63;
  const int quad = lane >> 4, l16 = lane & 15;
  const int wm = (wave & 1) * 32, wn = (wave >> 1) * 32;
  const int srow = tid >> 2, scol = (tid & 3) * 8;
  const float* Ag = A + (long)(m0 + srow) * lda + scol;
  const float* Bg = B + (long)(n0 + srow) * ldb + scol;
  float ra[2][8], rb[2][8];
  auto gload = [&](int kt, int s) {
    long k = (long)kt * 32;
    *(float4*)(ra[s])     = *(const float4*)(Ag + k);
    *(float4*)(ra[s] + 4) = *(const float4*)(Ag + k + 4);
    *(float4*)(rb[s])     = *(const float4*)(Bg + k);
    *(float4*)(rb[s] + 4) = *(const float4*)(Bg + k + 4);
  };
  f32x4 acc[2][2] = {};
  gload(0, 0); gload(1, 1);
  for (int kt = 0; kt < NT; ++kt) {
    const int s = kt & 1;
    short* As = lds + s * 4096;
    short* Bs = As + 2048;
    *(s16x8*)&As[srow * 32 + scol] = cvt8(ra[s]);
    *(s16x8*)&Bs[srow * 32 + scol] = cvt8(rb[s]);
    __syncthreads();
    if (kt + 2 < NT) gload(kt + 2, s);   // 2 iters of latency cover
    bf16x8 a0 = *(const bf16x8*)&As[(wm + l16) * 32 + quad * 8];
    bf16x8 a1 = *(const bf16x8*)&As[(wm + 16 + l16) * 32 + quad * 8];
    bf16x8 b0 = *(const bf16x8*)&Bs[(wn + l16) * 32 + quad * 8];
    bf16x8 b1 = *(const bf16x8*)&Bs[(wn + 16 + l16) * 32 + quad * 8];
    acc[0][0] = MFMA16(a0, b0, acc[0][0], 0, 0, 0);
    acc[0][1] = MFMA16(a0, b1, acc[0][1], 0, 0, 0);
    acc[1][0] = MFMA16(a1, b0, acc[1][0], 0, 0, 0);
    acc[1][1] = MFMA16(a1, b1, acc[1][1], 0, 0, 0);
  }
  #pragma unroll
  for (int i = 0; i < 2; ++i)
    #pragma unroll
    for (int j = 0; j < 2; ++j) {
      int col = n0 + wn + j * 16 + l16;
      #pragma unroll
      for (int r = 0; r < 4; ++r) {
        int row = m0 + wm + i * 16 + quad * 4 + r;
        C[(long)row * ldc + col] = f2bf(acc[i][j][r]);
      }
    }
}

// ---- bf16-input 64x64 GEMM: global_load_lds PD=4 ring, ONE barrier/iter ----
// Order per iter: wait own-slice vmcnt -> barrier (tile published) ->
// issue kt+3 (safe: last readers of that buf were iter kt-1, pre-barrier) -> read+MFMA.
// EPI 1 (Weff): v += e0[row*1536+col] (f32 Wo1), store bf16.
// EPI 2 (out):  v += e0[col] + e1[row]*e2[col], store f32.
template <int EPI>
__device__ void bgemm64(const short* __restrict__ A, int lda,
                        const short* __restrict__ B, int ldb,
                        void* __restrict__ C, int ldc, int NT, int m0, int n0,
                        const float* __restrict__ e0, const float* __restrict__ e1,
                        const float* __restrict__ e2, short* lds) {
  short* As = lds;               // 4 bufs * 2048 shorts
  short* Bs = lds + 4 * 2048;
  const int tid = threadIdx.x;
  const int wave = tid >> 6, lane = tid & 63;
  const int quad = lane >> 4, l16 = lane & 15;
  const int wm = (wave & 1) * 32, wn = (wave >> 1) * 32;
  const int srow = tid >> 2, scol = (tid & 3) * 8;
  const short* Ag = A + (long)(m0 + srow) * lda + scol;
  const short* Bg = B + (long)(n0 + srow) * ldb + scol;
  const int ldsoff = wave * 512;  // wave-uniform base (16 rows/wave)
  auto issue = [&](int kt) {
    int buf = kt & 3; int ko = kt * 32;
    __builtin_amdgcn_global_load_lds((gas_t)(Ag + ko), (las_t)(As + buf * 2048 + ldsoff), 16, 0, 0);
    __builtin_amdgcn_global_load_lds((gas_t)(Bg + ko), (las_t)(Bs + buf * 2048 + ldsoff), 16, 0, 0);
  };
  f32x4 acc[2][2] = {};
  issue(0); issue(1); issue(2);
  for (int kt = 0; kt < NT; ++kt) {
    int rem = NT - 1 - kt;
    if (rem >= 2)      asm volatile("s_waitcnt vmcnt(4)" ::: "memory");
    else if (rem == 1) asm volatile("s_waitcnt vmcnt(2)" ::: "memory");
    else               asm volatile("s_waitcnt vmcnt(0)" ::: "memory");
    asm volatile("s_barrier" ::: "memory");
    if (kt + 3 < NT) issue(kt + 3);
    const short* as = As + (kt & 3) * 2048;
    const short* bs = Bs + (kt & 3) * 2048;
    bf16x8 a0 = *(const bf16x8*)&as[(wm + l16) * 32 + quad * 8];
    bf16x8 a1 = *(const bf16x8*)&as[(wm + 16 + l16) * 32 + quad * 8];
    bf16x8 b0 = *(const bf16x8*)&bs[(wn + l16) * 32 + quad * 8];
    bf16x8 b1 = *(const bf16x8*)&bs[(wn + 16 + l16) * 32 + quad * 8];
    acc[0][0] = MFMA16(a0, b0, acc[0][0], 0, 0, 0);
    acc[0][1] = MFMA16(a0, b1, acc[0][1], 0, 0, 0);
    acc[1][0] = MFMA16(a1, b0, acc[1][0], 0, 0, 0);
    acc[1][1] = MFMA16(a1, b1, acc[1][1], 0, 0, 0);
  }
  #pragma unroll
  for (int i = 0; i < 2; ++i)
    #pragma unroll
    for (int j = 0; j < 2; ++j) {
      int col = n0 + wn + j * 16 + l16;
      #pragma unroll
      for (int r = 0; r < 4; ++r) {
        int row = m0 + wm + i * 16 + quad * 4 + r;
        float v = acc[i][j][r];
        if constexpr (EPI == 1) {
          v += e0[(long)row * 1536 + col];
          ((short*)C)[(long)row * ldc + col] = f2bf(v);
        } else {
          v += e0[col] + e1[row] * e2[col];
          ((float*)C)[(long)row * ldc + col] = v;
        }
      }
    }
}

// ---- vu gate tile 32(M)x64(N): PD=2 LDS + 2-deep reg prefetch, 1 barrier/iter ----
// lds layout: buf s at lds + s*5120 (As 1024, Bvs 2048, Bus 2048 shorts).
__device__ void vu_tile(int mi, int ni, const float* __restrict__ X,
                        const float* __restrict__ Wv, const float* __restrict__ Wu,
                        const float* __restrict__ bv, const float* __restrict__ bu,
                        const float* __restrict__ Wa, float* __restrict__ wpart,
                        short* lds, float* red) {
  const int tid = threadIdx.x, wave = tid >> 6, lane = tid & 63;
  const int quad = lane >> 4, l16 = lane & 15;
  const int wm = (wave & 1) * 16, wn = (wave >> 1) * 32;
  const int m0 = mi * 32, n0 = ni * 64;
  const int srow = tid >> 2, scol = (tid & 3) * 8;
  const float* Ag  = X  + (long)(m0 + srow) * 1024 + scol;   // valid only tid<128
  const float* Bvg = Wv + (long)(n0 + srow) * 1024 + scol;
  const float* Bug = Wu + (long)(n0 + srow) * 1024 + scol;
  float ra[2][8], rv[2][8], ru[2][8];
  auto gload = [&](int kt, int s) {
    long k = (long)kt * 32;
    if (tid < 128) {
      *(float4*)(ra[s])     = *(const float4*)(Ag + k);
      *(float4*)(ra[s] + 4) = *(const float4*)(Ag + k + 4);
    }
    *(float4*)(rv[s])     = *(const float4*)(Bvg + k);
    *(float4*)(rv[s] + 4) = *(const float4*)(Bvg + k + 4);
    *(float4*)(ru[s])     = *(const float4*)(Bug + k);
    *(float4*)(ru[s] + 4) = *(const float4*)(Bug + k + 4);
  };
  f32x4 accv[2] = {}, accu[2] = {};
  gload(0, 0); gload(1, 1);
  for (int kt = 0; kt < 32; ++kt) {
    const int s = kt & 1;
    short* As  = lds + s * 5120;
    short* Bvs = As + 1024;
    short* Bus = As + 3072;
    if (tid < 128) *(s16x8*)&As[srow * 32 + scol] = cvt8(ra[s]);
    *(s16x8*)&Bvs[srow * 32 + scol] = cvt8(rv[s]);
    *(s16x8*)&Bus[srow * 32 + scol] = cvt8(ru[s]);
    __syncthreads();
    if (kt + 2 < 32) gload(kt + 2, s);
    bf16x8 af = *(const bf16x8*)&As[(wm + l16) * 32 + quad * 8];
    bf16x8 v0 = *(const bf16x8*)&Bvs[(wn + l16) * 32 + quad * 8];
    bf16x8 v1 = *(const bf16x8*)&Bvs[(wn + 16 + l16) * 32 + quad * 8];
    bf16x8 u0 = *(const bf16x8*)&Bus[(wn + l16) * 32 + quad * 8];
    bf16x8 u1 = *(const bf16x8*)&Bus[(wn + 16 + l16) * 32 + quad * 8];
    accv[0] = MFMA16(af, v0, accv[0], 0, 0, 0);
    accv[1] = MFMA16(af, v1, accv[1], 0, 0, 0);
    accu[0] = MFMA16(af, u0, accu[0], 0, 0, 0);
    accu[1] = MFMA16(af, u1, accu[1], 0, 0, 0);
  }
  float wsum[4] = {0.f, 0.f, 0.f, 0.f};
  #pragma unroll
  for (int j = 0; j < 2; ++j) {
    int col = n0 + wn + j * 16 + l16;
    float bvc = bv[col], buc = bu[col], wac = Wa[col];
    #pragma unroll
    for (int r = 0; r < 4; ++r) {
      float vv = tanhf(accv[j][r] + bvc);
      float uu = accu[j][r] + buc;
      wsum[r] += (vv / (1.0f + expf(-uu))) * wac;
    }
  }
  #pragma unroll
  for (int r = 0; r < 4; ++r) {
    float s = wsum[r];
    s += __shfl_down(s, 8, 16);
    s += __shfl_down(s, 4, 16);
    s += __shfl_down(s, 2, 16);
    s += __shfl_down(s, 1, 16);
    if (l16 == 0) red[(wave >> 1) * 32 + wm + quad * 4 + r] = s;
  }
  __syncthreads();
  if (tid < 32) wpart[ni * 2048 + m0 + tid] = red[tid] + red[32 + tid];
}

// ---- masked softmax over K=16 + pooling for one entity -> er (bf16), cf ----
__device__ void softmax_entity(int be, const float* __restrict__ ment,
    const int* __restrict__ ents, const int* __restrict__ msk,
    const float* __restrict__ wpart, const float* __restrict__ br,
    short* __restrict__ erb, float* __restrict__ cf,
    float* sm_a, int* sm_idx, float* sm_red) {
  const int b = be >> 7;  // E=128
  const int tid = threadIdx.x;
  __syncthreads();  // protect shared reuse across entities
  if (tid < 16) {
    int idx = ents[be * 16 + tid];
    sm_idx[tid] = idx;
    int j = (b << 8) + idx;
    float lw = wpart[j] + wpart[2048 + j] + wpart[4096 + j] + wpart[6144 + j];
    sm_a[tid] = msk[be * 16 + tid] ? lw : NEG_;
  }
  __syncthreads();
  if (tid == 0) {
    float mx = sm_a[0];
    #pragma unroll
    for (int k = 1; k < 16; ++k) mx = fmaxf(mx, sm_a[k]);
    float e[16], s = 0.f;
    #pragma unroll
    for (int k = 0; k < 16; ++k) { e[k] = expf(sm_a[k] - mx); s += e[k]; }
    float inv = 1.0f / s;
    #pragma unroll
    for (int k = 0; k < 16; ++k) sm_a[k] = e[k] * inv;
  }
  __syncthreads();
  const float* Xr = ment + ((long)b << 18);
  const int h0 = tid * 4;
  float ax = 0.f, ay = 0.f, az = 0.f, aw = 0.f;
  #pragma unroll
  for (int k = 0; k < 16; ++k) {
    float ak = sm_a[k];
    float4 xv = *(const float4*)&Xr[(long)sm_idx[k] * 1024 + h0];
    ax += ak * xv.x; ay += ak * xv.y; az += ak * xv.z; aw += ak * xv.w;
  }
  short* er = erb + (long)be * 1024 + h0;
  er[0] = f2bf(ax); er[1] = f2bf(ay); er[2] = f2bf(az); er[3] = f2bf(aw);
  float4 brv = *(const float4*)&br[h0];
  float c = ax * brv.x + ay * brv.y + az * brv.z + aw * brv.w;
  #pragma unroll
  for (int off = 32; off > 0; off >>= 1) c += __shfl_down(c, off);
  if ((tid & 63) == 0) sm_red[tid >> 6] = c;
  __syncthreads();
  if (tid == 0) cf[be] = sm_red[0] + sm_red[1] + sm_red[2] + sm_red[3];
}

// ================= kernels =================
// L1: s_wT = Wr @ rm^T (256) | U = Wo2 @ rm^T (256) | vu gate (256)
__global__ __launch_bounds__(256) void k1(
    const float* __restrict__ rm, const float* __restrict__ ment,
    const float* __restrict__ Wv, const float* __restrict__ Wu,
    const float* __restrict__ bv, const float* __restrict__ bu,
    const float* __restrict__ Wa, const float* __restrict__ Wr,
    const float* __restrict__ Wo, short* __restrict__ swTb,
    short* __restrict__ Ub, float* __restrict__ wpart) {
  __shared__ short lds[10240];   // 20 KB: fgemm uses 16 KB, vu uses 20 KB
  __shared__ float red[64];
  const int blk = blockIdx.x;
  if (blk < 256) {
    fgemm64<16>(Wr, 512, rm, 512, swTb, 1024, (blk >> 4) * 64, (blk & 15) * 64, lds);
  } else if (blk < 512) {
    int q = blk - 256;
    fgemm64<16>(Wo + 1024, 1536, rm, 512, Ub, 1024, (q >> 4) * 64, (q & 15) * 64, lds);
  } else {
    int q = blk - 512;                 // ni-outer: same-X blocks spread rows
    vu_tile(q & 63, q >> 6, ment, Wv, Wu, bv, bu, Wa, wpart, lds, red);
  }
}

// L2: Weff = Wo1 + U @ s_wT^T (256) | gw2 = rowsum(U) (4) | softmax (256)
__global__ __launch_bounds__(256) void k2(
    const short* __restrict__ Ub, const short* __restrict__ swTb,
    const float* __restrict__ Wo, const float* __restrict__ ment,
    const int* __restrict__ ents, const int* __restrict__ msk,
    const float* __restrict__ wpart, const float* __restrict__ br,
    short* __restrict__ Weffb, float* __restrict__ gw2,
    short* __restrict__ erb, float* __restrict__ cf) {
  __shared__ short lds[16384];
  __shared__ float sm_a[16];
  __shared__ int   sm_idx[16];
  __shared__ float sm_red[4];
  const int blk = blockIdx.x, tid = threadIdx.x;
  if (blk < 256) {
    bgemm64<1>(Ub, 1024, swTb, 1024, Weffb, 1024, 32,
               (blk >> 4) * 64, (blk & 15) * 64, Wo, nullptr, nullptr, lds);
  } else if (blk < 260) {
    int row = (blk - 256) * 256 + tid;
    const short* u = Ub + (long)row * 1024;
    float s = 0.f;
    for (int k = 0; k < 1024; k += 8) {
      s16x8 v = *(const s16x8*)&u[k];
      union { s16x8 s; bf16x8 b; } w; w.s = v;
      #pragma unroll
      for (int j = 0; j < 8; ++j) s += (float)w.b[j];
    }
    gw2[row] = s;
  } else {
    int s4 = (blk - 260) * 4;
    for (int e = 0; e < 4; ++e)
      softmax_entity(s4 + e, ment, ents, msk, wpart, br, erb, cf,
                     sm_a, sm_idx, sm_red);
  }
}

// L3: out = er @ Weff^T + bo + cf*gw2 (256)
__global__ __launch_bounds__(256) void k3(
    const short* __restrict__ erb, const short* __restrict__ Weffb,
    const float* __restrict__ bo, const float* __restrict__ cf,
    const float* __restrict__ gw2, float* __restrict__ out) {
  __shared__ short lds[16384];
  const int blk = blockIdx.x;
  bgemm64<2>(erb, 1024, Weffb, 1024, out, 1024, 32,
             (blk >> 4) * 64, (blk & 15) * 64, bo, cf, gw2, lds);
}

extern "C" void kernel_launch(void* const* d_in, const int* in_sizes, int n_in,
                              void* d_out, int out_size, void* d_ws, size_t ws_size,
                              hipStream_t stream) {
  const float* ment = (const float*)d_in[0];
  const int*   ents = (const int*)d_in[1];
  const int*   msk  = (const int*)d_in[2];
  const float* rm   = (const float*)d_in[3];
  const float* Wv   = (const float*)d_in[4];
  const float* bv   = (const float*)d_in[5];
  const float* Wu   = (const float*)d_in[6];
  const float* bu   = (const float*)d_in[7];
  const float* Wa   = (const float*)d_in[8];
  // d_in[9] = ba: drops out (softmax shift-invariance)
  const float* Wr   = (const float*)d_in[10];
  const float* br   = (const float*)d_in[11];
  const float* Wo   = (const float*)d_in[12];
  const float* bo   = (const float*)d_in[13];
  float* out = (float*)d_out;

  char* p = (char*)d_ws;
  auto alloc = [&](size_t bytes) {
    void* q = (void*)p; p += (bytes + 255) & ~(size_t)255; return q;
  };
  short* swTb  = (short*)alloc((size_t)1024 * 1024 * 2);  // s_wT[j,r] bf16
  short* Ub    = (short*)alloc((size_t)1024 * 1024 * 2);  // U[h,r] bf16
  short* Weffb = (short*)alloc((size_t)1024 * 1024 * 2);  // Wo1 + U@s_wT^T bf16
  short* erb   = (short*)alloc((size_t)1024 * 1024 * 2);  // entity reprs bf16
  float* wpart = (float*)alloc((size_t)4 * 2048 * 4);     // gate partials
  float* cf    = (float*)alloc((size_t)1024 * 4);         // er . br
  float* gw2   = (float*)alloc((size_t)1024 * 4);         // rowsum(U)

  k1<<<768, 256, 0, stream>>>(rm, ment, Wv, Wu, bv, bu, Wa, Wr, Wo,
                              swTb, Ub, wpart);
  k2<<<516, 256, 0, stream>>>(Ub, swTb, Wo, ment, ents, msk, wpart, br,
                              Weffb, gw2, erb, cf);
  k3<<<256, 256, 0, stream>>>(erb, Weffb, bo, cf, gw2, out);
}

// Round 8
// 139.647 us; speedup vs baseline: 1.3446x; 1.3446x over previous
//
#include <hip/hip_runtime.h>
#include <cstdint>
#include <cstddef>

#define NEG_ (-1e25f)

typedef __bf16 bf16x8 __attribute__((ext_vector_type(8)));
typedef float  f32x4  __attribute__((ext_vector_type(4)));
typedef short  s16x8  __attribute__((ext_vector_type(8)));
typedef const __attribute__((address_space(1))) void* gas_t;
typedef __attribute__((address_space(3))) void* las_t;

#define MFMA16 __builtin_amdgcn_mfma_f32_16x16x32_bf16

__device__ __forceinline__ short f2bf(float f) {
  union { float f; unsigned u; } v; v.f = f;
  unsigned r = v.u + 0x7fffu + ((v.u >> 16) & 1u);  // RNE
  return (short)(r >> 16);
}

__device__ __forceinline__ s16x8 cvt8(const float* s) {
  bf16x8 r;
  #pragma unroll
  for (int j = 0; j < 8; ++j) r[j] = (__bf16)s[j];  // fptrunc = RNE
  union { bf16x8 b; s16x8 s; } u; u.b = r; return u.s;
}

// ---- fused dual-A f32 GEMM: C1 = A1@B^T, C2 = A2@B^T (shared B tile) ----
// Single LDS buffer, 1-ahead STATIC register prefetch (no dynamic indexing ->
// no scratch spill), 8 MFMA per iter per wave pair of outputs.
template <int NT>
__device__ void fgemm_dual(const float* __restrict__ A1, long lda1,
                           const float* __restrict__ A2, long lda2,
                           const float* __restrict__ B, long ldb,
                           short* __restrict__ C1, short* __restrict__ C2,
                           int ldc, int m0, int n0, short* lds) {
  const int tid = threadIdx.x, wave = tid >> 6, lane = tid & 63;
  const int quad = lane >> 4, l16 = lane & 15;
  const int wm = (wave & 1) * 32, wn = (wave >> 1) * 32;
  const int srow = tid >> 2, scol = (tid & 3) * 8;
  const float* A1g = A1 + (long)(m0 + srow) * lda1 + scol;
  const float* A2g = A2 + (long)(m0 + srow) * lda2 + scol;
  const float* Bg  = B  + (long)(n0 + srow) * ldb + scol;
  short* As1 = lds;            // 64x32
  short* As2 = lds + 2048;     // 64x32
  short* Bs  = lds + 4096;     // 64x32
  float r1[8], r2[8], rb[8];
  auto gload = [&](int kt) {
    long k = (long)kt * 32;
    *(float4*)(r1)     = *(const float4*)(A1g + k);
    *(float4*)(r1 + 4) = *(const float4*)(A1g + k + 4);
    *(float4*)(r2)     = *(const float4*)(A2g + k);
    *(float4*)(r2 + 4) = *(const float4*)(A2g + k + 4);
    *(float4*)(rb)     = *(const float4*)(Bg + k);
    *(float4*)(rb + 4) = *(const float4*)(Bg + k + 4);
  };
  f32x4 acc1[2][2] = {}, acc2[2][2] = {};
  gload(0);
  for (int kt = 0; kt < NT; ++kt) {
    *(s16x8*)&As1[srow * 32 + scol] = cvt8(r1);
    *(s16x8*)&As2[srow * 32 + scol] = cvt8(r2);
    *(s16x8*)&Bs[srow * 32 + scol]  = cvt8(rb);
    __syncthreads();
    if (kt + 1 < NT) gload(kt + 1);  // prefetch overlaps frag reads + MFMA
    bf16x8 a10 = *(const bf16x8*)&As1[(wm + l16) * 32 + quad * 8];
    bf16x8 a11 = *(const bf16x8*)&As1[(wm + 16 + l16) * 32 + quad * 8];
    bf16x8 a20 = *(const bf16x8*)&As2[(wm + l16) * 32 + quad * 8];
    bf16x8 a21 = *(const bf16x8*)&As2[(wm + 16 + l16) * 32 + quad * 8];
    bf16x8 b0  = *(const bf16x8*)&Bs[(wn + l16) * 32 + quad * 8];
    bf16x8 b1  = *(const bf16x8*)&Bs[(wn + 16 + l16) * 32 + quad * 8];
    acc1[0][0] = MFMA16(a10, b0, acc1[0][0], 0, 0, 0);
    acc1[0][1] = MFMA16(a10, b1, acc1[0][1], 0, 0, 0);
    acc1[1][0] = MFMA16(a11, b0, acc1[1][0], 0, 0, 0);
    acc1[1][1] = MFMA16(a11, b1, acc1[1][1], 0, 0, 0);
    acc2[0][0] = MFMA16(a20, b0, acc2[0][0], 0, 0, 0);
    acc2[0][1] = MFMA16(a20, b1, acc2[0][1], 0, 0, 0);
    acc2[1][0] = MFMA16(a21, b0, acc2[1][0], 0, 0, 0);
    acc2[1][1] = MFMA16(a21, b1, acc2[1][1], 0, 0, 0);
    __syncthreads();
  }
  #pragma unroll
  for (int i = 0; i < 2; ++i)
    #pragma unroll
    for (int j = 0; j < 2; ++j) {
      int col = n0 + wn + j * 16 + l16;
      #pragma unroll
      for (int r = 0; r < 4; ++r) {
        int row = m0 + wm + i * 16 + quad * 4 + r;
        C1[(long)row * ldc + col] = f2bf(acc1[i][j][r]);
        C2[(long)row * ldc + col] = f2bf(acc2[i][j][r]);
      }
    }
}

// ---- bf16-input 64x64 GEMM: global_load_lds PD=4 ring, ONE barrier/iter ----
// EPI 1 (Weff): v += e0[row*1536+col] (f32 Wo1), store bf16.
// EPI 2 (out):  v += e0[col] + e1[row]*e2[col], store f32.
template <int EPI>
__device__ void bgemm64(const short* __restrict__ A, int lda,
                        const short* __restrict__ B, int ldb,
                        void* __restrict__ C, int ldc, int NT, int m0, int n0,
                        const float* __restrict__ e0, const float* __restrict__ e1,
                        const float* __restrict__ e2, short* lds) {
  short* As = lds;               // 4 bufs * 2048 shorts
  short* Bs = lds + 4 * 2048;
  const int tid = threadIdx.x;
  const int wave = tid >> 6, lane = tid & 63;
  const int quad = lane >> 4, l16 = lane & 15;
  const int wm = (wave & 1) * 32, wn = (wave >> 1) * 32;
  const int srow = tid >> 2, scol = (tid & 3) * 8;
  const short* Ag = A + (long)(m0 + srow) * lda + scol;
  const short* Bg = B + (long)(n0 + srow) * ldb + scol;
  const int ldsoff = wave * 512;  // wave-uniform base (16 rows/wave)
  auto issue = [&](int kt) {
    int buf = kt & 3; int ko = kt * 32;
    __builtin_amdgcn_global_load_lds((gas_t)(Ag + ko), (las_t)(As + buf * 2048 + ldsoff), 16, 0, 0);
    __builtin_amdgcn_global_load_lds((gas_t)(Bg + ko), (las_t)(Bs + buf * 2048 + ldsoff), 16, 0, 0);
  };
  f32x4 acc[2][2] = {};
  issue(0); issue(1); issue(2);
  for (int kt = 0; kt < NT; ++kt) {
    int rem = NT - 1 - kt;
    if (rem >= 2)      asm volatile("s_waitcnt vmcnt(4)" ::: "memory");
    else if (rem == 1) asm volatile("s_waitcnt vmcnt(2)" ::: "memory");
    else               asm volatile("s_waitcnt vmcnt(0)" ::: "memory");
    asm volatile("s_barrier" ::: "memory");
    if (kt + 3 < NT) issue(kt + 3);
    const short* as = As + (kt & 3) * 2048;
    const short* bs = Bs + (kt & 3) * 2048;
    bf16x8 a0 = *(const bf16x8*)&as[(wm + l16) * 32 + quad * 8];
    bf16x8 a1 = *(const bf16x8*)&as[(wm + 16 + l16) * 32 + quad * 8];
    bf16x8 b0 = *(const bf16x8*)&bs[(wn + l16) * 32 + quad * 8];
    bf16x8 b1 = *(const bf16x8*)&bs[(wn + 16 + l16) * 32 + quad * 8];
    acc[0][0] = MFMA16(a0, b0, acc[0][0], 0, 0, 0);
    acc[0][1] = MFMA16(a0, b1, acc[0][1], 0, 0, 0);
    acc[1][0] = MFMA16(a1, b0, acc[1][0], 0, 0, 0);
    acc[1][1] = MFMA16(a1, b1, acc[1][1], 0, 0, 0);
  }
  #pragma unroll
  for (int i = 0; i < 2; ++i)
    #pragma unroll
    for (int j = 0; j < 2; ++j) {
      int col = n0 + wn + j * 16 + l16;
      #pragma unroll
      for (int r = 0; r < 4; ++r) {
        int row = m0 + wm + i * 16 + quad * 4 + r;
        float v = acc[i][j][r];
        if constexpr (EPI == 1) {
          v += e0[(long)row * 1536 + col];
          ((short*)C)[(long)row * ldc + col] = f2bf(v);
        } else {
          v += e0[col] + e1[row] * e2[col];
          ((float*)C)[(long)row * ldc + col] = v;
        }
      }
    }
}

// ---- vu gate tile 32(M)x64(N), R6-proven: single buffer, static reg prefetch ----
__device__ void vu_tile(int mi, int ni, const float* __restrict__ X,
                        const float* __restrict__ Wv, const float* __restrict__ Wu,
                        const float* __restrict__ bv, const float* __restrict__ bu,
                        const float* __restrict__ Wa, float* __restrict__ wpart,
                        short* lds, float* red) {
  const int tid = threadIdx.x, wave = tid >> 6, lane = tid & 63;
  const int quad = lane >> 4, l16 = lane & 15;
  const int wm = (wave & 1) * 16, wn = (wave >> 1) * 32;
  const int m0 = mi * 32, n0 = ni * 64;
  const int srow = tid >> 2, scol = (tid & 3) * 8;
  short* As = lds;          // 32x32
  short* Bvs = lds + 1024;  // 64x32
  short* Bus = lds + 3072;  // 64x32
  const float* Ag  = X  + (long)(m0 + srow) * 1024 + scol;   // valid only tid<128
  const float* Bvg = Wv + (long)(n0 + srow) * 1024 + scol;
  const float* Bug = Wu + (long)(n0 + srow) * 1024 + scol;
  float ra[8], rv[8], ru[8];
  auto gload = [&](int kt) {
    long k = (long)kt * 32;
    if (tid < 128) {
      *(float4*)(ra)     = *(const float4*)(Ag + k);
      *(float4*)(ra + 4) = *(const float4*)(Ag + k + 4);
    }
    *(float4*)(rv)     = *(const float4*)(Bvg + k);
    *(float4*)(rv + 4) = *(const float4*)(Bvg + k + 4);
    *(float4*)(ru)     = *(const float4*)(Bug + k);
    *(float4*)(ru + 4) = *(const float4*)(Bug + k + 4);
  };
  f32x4 accv[2] = {}, accu[2] = {};
  gload(0);
  for (int kt = 0; kt < 32; ++kt) {
    if (tid < 128) *(s16x8*)&As[srow * 32 + scol] = cvt8(ra);
    *(s16x8*)&Bvs[srow * 32 + scol] = cvt8(rv);
    *(s16x8*)&Bus[srow * 32 + scol] = cvt8(ru);
    __syncthreads();
    if (kt + 1 < 32) gload(kt + 1);
    bf16x8 af = *(const bf16x8*)&As[(wm + l16) * 32 + quad * 8];
    bf16x8 v0 = *(const bf16x8*)&Bvs[(wn + l16) * 32 + quad * 8];
    bf16x8 v1 = *(const bf16x8*)&Bvs[(wn + 16 + l16) * 32 + quad * 8];
    bf16x8 u0 = *(const bf16x8*)&Bus[(wn + l16) * 32 + quad * 8];
    bf16x8 u1 = *(const bf16x8*)&Bus[(wn + 16 + l16) * 32 + quad * 8];
    accv[0] = MFMA16(af, v0, accv[0], 0, 0, 0);
    accv[1] = MFMA16(af, v1, accv[1], 0, 0, 0);
    accu[0] = MFMA16(af, u0, accu[0], 0, 0, 0);
    accu[1] = MFMA16(af, u1, accu[1], 0, 0, 0);
    __syncthreads();
  }
  float wsum[4] = {0.f, 0.f, 0.f, 0.f};
  #pragma unroll
  for (int j = 0; j < 2; ++j) {
    int col = n0 + wn + j * 16 + l16;
    float bvc = bv[col], buc = bu[col], wac = Wa[col];
    #pragma unroll
    for (int r = 0; r < 4; ++r) {
      float vv = tanhf(accv[j][r] + bvc);
      float uu = accu[j][r] + buc;
      wsum[r] += (vv / (1.0f + expf(-uu))) * wac;
    }
  }
  #pragma unroll
  for (int r = 0; r < 4; ++r) {
    float s = wsum[r];
    s += __shfl_down(s, 8, 16);
    s += __shfl_down(s, 4, 16);
    s += __shfl_down(s, 2, 16);
    s += __shfl_down(s, 1, 16);
    if (l16 == 0) red[(wave >> 1) * 32 + wm + quad * 4 + r] = s;
  }
  __syncthreads();
  if (tid < 32) wpart[ni * 2048 + m0 + tid] = red[tid] + red[32 + tid];
}

// ---- masked softmax over K=16 + pooling for one entity -> er (bf16), cf ----
__device__ void softmax_entity(int be, const float* __restrict__ ment,
    const int* __restrict__ ents, const int* __restrict__ msk,
    const float* __restrict__ wpart, const float* __restrict__ br,
    short* __restrict__ erb, float* __restrict__ cf,
    float* sm_a, int* sm_idx, float* sm_red) {
  const int b = be >> 7;  // E=128
  const int tid = threadIdx.x;
  __syncthreads();  // protect shared reuse across entities
  if (tid < 16) {
    int idx = ents[be * 16 + tid];
    sm_idx[tid] = idx;
    int j = (b << 8) + idx;
    float lw = wpart[j] + wpart[2048 + j] + wpart[4096 + j] + wpart[6144 + j];
    sm_a[tid] = msk[be * 16 + tid] ? lw : NEG_;
  }
  __syncthreads();
  if (tid == 0) {
    float mx = sm_a[0];
    #pragma unroll
    for (int k = 1; k < 16; ++k) mx = fmaxf(mx, sm_a[k]);
    float e[16], s = 0.f;
    #pragma unroll
    for (int k = 0; k < 16; ++k) { e[k] = expf(sm_a[k] - mx); s += e[k]; }
    float inv = 1.0f / s;
    #pragma unroll
    for (int k = 0; k < 16; ++k) sm_a[k] = e[k] * inv;
  }
  __syncthreads();
  const float* Xr = ment + ((long)b << 18);
  const int h0 = tid * 4;
  float ax = 0.f, ay = 0.f, az = 0.f, aw = 0.f;
  #pragma unroll
  for (int k = 0; k < 16; ++k) {
    float ak = sm_a[k];
    float4 xv = *(const float4*)&Xr[(long)sm_idx[k] * 1024 + h0];
    ax += ak * xv.x; ay += ak * xv.y; az += ak * xv.z; aw += ak * xv.w;
  }
  short* er = erb + (long)be * 1024 + h0;
  er[0] = f2bf(ax); er[1] = f2bf(ay); er[2] = f2bf(az); er[3] = f2bf(aw);
  float4 brv = *(const float4*)&br[h0];
  float c = ax * brv.x + ay * brv.y + az * brv.z + aw * brv.w;
  #pragma unroll
  for (int off = 32; off > 0; off >>= 1) c += __shfl_down(c, off);
  if ((tid & 63) == 0) sm_red[tid >> 6] = c;
  __syncthreads();
  if (tid == 0) cf[be] = sm_red[0] + sm_red[1] + sm_red[2] + sm_red[3];
}

// ================= kernels =================
// L1: fused {s_wT = Wr @ rm^T, U = Wo2 @ rm^T} (256) | vu gate (256)
__global__ __launch_bounds__(256) void k1(
    const float* __restrict__ rm, const float* __restrict__ ment,
    const float* __restrict__ Wv, const float* __restrict__ Wu,
    const float* __restrict__ bv, const float* __restrict__ bu,
    const float* __restrict__ Wa, const float* __restrict__ Wr,
    const float* __restrict__ Wo, short* __restrict__ swTb,
    short* __restrict__ Ub, float* __restrict__ wpart) {
  __shared__ short lds[6144];    // 12 KB: dual fgemm 3 slabs; vu uses 5120
  __shared__ float red[64];
  const int blk = blockIdx.x;
  if (blk < 256) {
    fgemm_dual<16>(Wr, 512, Wo + 1024, 1536, rm, 512, swTb, Ub, 1024,
                   (blk >> 4) * 64, (blk & 15) * 64, lds);
  } else {
    int q = blk - 256;                 // ni-outer: same-X blocks spread rows
    vu_tile(q & 63, q >> 6, ment, Wv, Wu, bv, bu, Wa, wpart, lds, red);
  }
}

// L2: Weff = Wo1 + U @ s_wT^T (256) | gw2 = rowsum(U) (4) | softmax (256)
__global__ __launch_bounds__(256) void k2(
    const short* __restrict__ Ub, const short* __restrict__ swTb,
    const float* __restrict__ Wo, const float* __restrict__ ment,
    const int* __restrict__ ents, const int* __restrict__ msk,
    const float* __restrict__ wpart, const float* __restrict__ br,
    short* __restrict__ Weffb, float* __restrict__ gw2,
    short* __restrict__ erb, float* __restrict__ cf) {
  __shared__ short lds[16384];
  __shared__ float sm_a[16];
  __shared__ int   sm_idx[16];
  __shared__ float sm_red[4];
  const int blk = blockIdx.x, tid = threadIdx.x;
  if (blk < 256) {
    bgemm64<1>(Ub, 1024, swTb, 1024, Weffb, 1024, 32,
               (blk >> 4) * 64, (blk & 15) * 64, Wo, nullptr, nullptr, lds);
  } else if (blk < 260) {
    int row = (blk - 256) * 256 + tid;
    const short* u = Ub + (long)row * 1024;
    float s = 0.f;
    for (int k = 0; k < 1024; k += 8) {
      s16x8 v = *(const s16x8*)&u[k];
      union { s16x8 s; bf16x8 b; } w; w.s = v;
      #pragma unroll
      for (int j = 0; j < 8; ++j) s += (float)w.b[j];
    }
    gw2[row] = s;
  } else {
    int s4 = (blk - 260) * 4;
    for (int e = 0; e < 4; ++e)
      softmax_entity(s4 + e, ment, ents, msk, wpart, br, erb, cf,
                     sm_a, sm_idx, sm_red);
  }
}

// L3: out = er @ Weff^T + bo + cf*gw2 (256)
__global__ __launch_bounds__(256) void k3(
    const short* __restrict__ erb, const short* __restrict__ Weffb,
    const float* __restrict__ bo, const float* __restrict__ cf,
    const float* __restrict__ gw2, float* __restrict__ out) {
  __shared__ short lds[16384];
  const int blk = blockIdx.x;
  bgemm64<2>(erb, 1024, Weffb, 1024, out, 1024, 32,
             (blk >> 4) * 64, (blk & 15) * 64, bo, cf, gw2, lds);
}

extern "C" void kernel_launch(void* const* d_in, const int* in_sizes, int n_in,
                              void* d_out, int out_size, void* d_ws, size_t ws_size,
                              hipStream_t stream) {
  const float* ment = (const float*)d_in[0];
  const int*   ents = (const int*)d_in[1];
  const int*   msk  = (const int*)d_in[2];
  const float* rm   = (const float*)d_in[3];
  const float* Wv   = (const float*)d_in[4];
  const float* bv   = (const float*)d_in[5];
  const float* Wu   = (const float*)d_in[6];
  const float* bu   = (const float*)d_in[7];
  const float* Wa   = (const float*)d_in[8];
  // d_in[9] = ba: drops out (softmax shift-invariance)
  const float* Wr   = (const float*)d_in[10];
  const float* br   = (const float*)d_in[11];
  const float* Wo   = (const float*)d_in[12];
  const float* bo   = (const float*)d_in[13];
  float* out = (float*)d_out;

  char* p = (char*)d_ws;
  auto alloc = [&](size_t bytes) {
    void* q = (void*)p; p += (bytes + 255) & ~(size_t)255; return q;
  };
  short* swTb  = (short*)alloc((size_t)1024 * 1024 * 2);  // s_wT[j,r] bf16
  short* Ub    = (short*)alloc((size_t)1024 * 1024 * 2);  // U[h,r] bf16
  short* Weffb = (short*)alloc((size_t)1024 * 1024 * 2);  // Wo1 + U@s_wT^T bf16
  short* erb   = (short*)alloc((size_t)1024 * 1024 * 2);  // entity reprs bf16
  float* wpart = (float*)alloc((size_t)4 * 2048 * 4);     // gate partials
  float* cf    = (float*)alloc((size_t)1024 * 4);         // er . br
  float* gw2   = (float*)alloc((size_t)1024 * 4);         // rowsum(U)

  k1<<<512, 256, 0, stream>>>(rm, ment, Wv, Wu, bv, bu, Wa, Wr, Wo,
                              swTb, Ub, wpart);
  k2<<<516, 256, 0, stream>>>(Ub, swTb, Wo, ment, ents, msk, wpart, br,
                              Weffb, gw2, erb, cf);
  k3<<<256, 256, 0, stream>>>(erb, Weffb, bo, cf, gw2, out);
}